// Round 6
// baseline (399.739 us; speedup 1.0000x reference)
//
#include <hip/hip_runtime.h>
#include <cmath>

#define NN 50000
#define NE 800000
// int32-overflow boundary of the reference's argsort key (jax x64 disabled):
// key = dst*50000+src wraps for dst>42949, or dst==42949 && src>=33648.
// VERIFIED round 3: jax order = rotate(bucket, s0), norm indexed by UNROTATED j.
#define DST_HI 42949
#define SRC_CUT 33648

// ---- rptr (CSR by src, binary search) + dout segment-sum, fused ----
__global__ __launch_bounds__(256) void k_rowdeg(const int* __restrict__ src, const float* __restrict__ w,
                                                int* __restrict__ rptr, float* __restrict__ dout) {
  int i = blockIdx.x * 256 + threadIdx.x;
  if (i >= NN) return;
  int lo = 0, hi = NE;
  while (lo < hi) { int m = (lo + hi) >> 1; if (src[m] < i) lo = m + 1; else hi = m; }
  int lo2 = lo, hi2 = NE;
  while (lo2 < hi2) { int m = (lo2 + hi2) >> 1; if (src[m] < i + 1) lo2 = m + 1; else hi2 = m; }
  rptr[i] = lo;
  if (i == NN - 1) rptr[NN] = lo2;
  float a = 0.f;
  for (int p = lo; p < lo2; ++p) a += w[p];
  dout[i] = a;
}

// ---- dst histogram (1 atomic/edge) ----
__global__ __launch_bounds__(256) void k_cnt(const int* __restrict__ dst, int* __restrict__ cnt) {
  int e = blockIdx.x * 256 + threadIdx.x;
  if (e >= NE) return;
  atomicAdd(&cnt[dst[e]], 1);
}

// ---- 3-kernel exclusive scan of cnt -> sp (sp[NN] = NE) ----
__global__ void k_scan1(const int* __restrict__ cnt, int* __restrict__ outp, int* __restrict__ partials) {
  __shared__ int tmp[1024];
  int i = blockIdx.x * 1024 + threadIdx.x;
  int v = (i < NN) ? cnt[i] : 0;
  tmp[threadIdx.x] = v;
  __syncthreads();
  for (int off = 1; off < 1024; off <<= 1) {
    int t = (threadIdx.x >= (unsigned)off) ? tmp[threadIdx.x - off] : 0;
    __syncthreads();
    tmp[threadIdx.x] += t;
    __syncthreads();
  }
  if (i < NN) outp[i] = tmp[threadIdx.x] - v;  // exclusive
  if (threadIdx.x == 1023) partials[blockIdx.x] = tmp[1023];
}

__global__ void k_scan2(int* __restrict__ partials, int nb) {
  if (threadIdx.x == 0 && blockIdx.x == 0) {
    int s = 0;
    for (int i = 0; i < nb; ++i) { int v = partials[i]; partials[i] = s; s += v; }
  }
}

__global__ __launch_bounds__(256) void k_scan3(int* __restrict__ outp, const int* __restrict__ partials) {
  int i = blockIdx.x * 256 + threadIdx.x;
  if (i < NN) outp[i] += partials[i >> 10];
  else if (i == NN) outp[i] = NE;
}

// ---- scatter edge ids into dst buckets, then sort each bucket (== argsort by true (dst,src)) ----
__global__ __launch_bounds__(256) void k_bucket(const int* __restrict__ dst, const int* __restrict__ sp,
                                                int* __restrict__ fill, int* __restrict__ bucket) {
  int e = blockIdx.x * 256 + threadIdx.x;
  if (e >= NE) return;
  int d = dst[e];
  int slot = sp[d] + atomicAdd(&fill[d], 1);
  bucket[slot] = e;
}

__global__ __launch_bounds__(256) void k_sort(const int* __restrict__ sp, int* __restrict__ bucket) {
  int d = blockIdx.x * 256 + threadIdx.x;
  if (d >= NN) return;
  int b0 = sp[d], b1 = sp[d + 1];
  for (int i = b0 + 1; i < b1; ++i) {
    int v = bucket[i];
    int j = i - 1;
    while (j >= b0 && bucket[j] > v) { bucket[j + 1] = bucket[j]; --j; }
    bucket[j + 1] = v;
  }
}

// ---- din: gather segment sum over dst-buckets (order-invariant), 8 lanes/node ----
__global__ __launch_bounds__(256) void k_din(const int* __restrict__ sp, const int* __restrict__ bucket,
                                             const float* __restrict__ w, float* __restrict__ din) {
  int t = blockIdx.x * 256 + threadIdx.x;
  int r = t >> 3;
  if (r >= NN) return;
  int lane = t & 7;
  int b = sp[r], e = sp[r + 1];
  float a = 0.f;
  for (int j = b + lane; j < e; j += 8) a += w[bucket[j]];
  a += __shfl_down(a, 4, 8);
  a += __shfl_down(a, 2, 8);
  a += __shfl_down(a, 1, 8);
  if (lane == 0) din[r] = a;
}

// ---- rotation offset s0 = #edges with non-overflowing int32 key ----
__global__ void k_s0(const int* __restrict__ sp, const int* __restrict__ bucket,
                     const int* __restrict__ src, int* __restrict__ s0) {
  if (threadIdx.x != 0 || blockIdx.x != 0) return;
  int b0 = sp[DST_HI], b1 = sp[DST_HI + 1];
  int c = b0;
  for (int j = b0; j < b1; ++j)
    if (src[bucket[j]] < SRC_CUT) ++c;
  *s0 = c;
}

// ---- per-edge arrays for gather props:
//   fwd (CSC by dst bucket): col_fwd[j] = src[bucket[j]]   (nrm computed in-prop from dout)
//   rev (CSR by src): rnrm[bucket[(j+s0)%NE]] = 1/din[src[j]]  (rotation bijection, verified) ----
__global__ __launch_bounds__(256) void k_edge(const int* __restrict__ bucket, const int* __restrict__ src,
                                              const int* __restrict__ s0p,
                                              const float* __restrict__ din,
                                              int* __restrict__ col_fwd, float* __restrict__ rnrm) {
  int j = blockIdx.x * 256 + threadIdx.x;
  if (j >= NE) return;
  int e = bucket[j];
  col_fwd[j] = src[e];
  int idx = j + *s0p;
  if (idx >= NE) idx -= NE;
  rnrm[bucket[idx]] = 1.0f / din[src[j]];
}

// ---- fused pair of gather props (A and B independent): 8 lanes/row, float4/lane.
//      weight: nrmX if non-null, else 1/doutX[col].  out = mul*acc - sub (sub==nullptr -> acc) ----
__global__ __launch_bounds__(256) void k_prop2(const float* __restrict__ inA, const int* __restrict__ rpA,
                                               const int* __restrict__ colsA, const float* __restrict__ nrmA,
                                               const float* __restrict__ doutA, float* __restrict__ outA,
                                               const float* __restrict__ inB, const int* __restrict__ rpB,
                                               const int* __restrict__ colsB, const float* __restrict__ nrmB,
                                               const float* __restrict__ doutB, float* __restrict__ outB,
                                               const float* __restrict__ sub, float mul) {
  int t = blockIdx.x * 256 + threadIdx.x;
  const int half = NN * 8;
  const float* in; const int* rp; const int* cols; const float* nrm; const float* dw; float* out;
  if (t < half) { in = inA; rp = rpA; cols = colsA; nrm = nrmA; dw = doutA; out = outA; }
  else          { in = inB; rp = rpB; cols = colsB; nrm = nrmB; dw = doutB; out = outB; t -= half; }
  int r = t >> 3;
  if (r >= NN) return;
  int c4 = (t & 7) * 4;
  int b = rp[r], e = rp[r + 1];
  float ax = 0.f, ay = 0.f, az = 0.f, aw = 0.f;
  for (int p = b; p < e; ++p) {
    int col = cols[p];       // 8 lanes same addr -> broadcast
    float w = nrm ? nrm[p] : 1.0f / dw[col];
    const float4 xv = *(const float4*)&in[col * 32 + c4];
    ax += w * xv.x; ay += w * xv.y; az += w * xv.z; aw += w * xv.w;
  }
  float4 o;
  if (sub) {
    const float4 s = *(const float4*)&sub[r * 32 + c4];
    o.x = mul * ax - s.x; o.y = mul * ay - s.y; o.z = mul * az - s.z; o.w = mul * aw - s.w;
  } else {
    o.x = ax; o.y = ay; o.z = az; o.w = aw;
  }
  *(float4*)&out[r * 32 + c4] = o;
}

// ---- effective weights (160 x 128): rows = [X|T1o|T1i|T2o|T2i]x32, cols 0..63=z, 64..127=h ----
__global__ __launch_bounds__(256) void k_weff(const float* __restrict__ Wz, const float* __restrict__ Wh,
                                              float* __restrict__ Weff) {
  int idx = blockIdx.x * 256 + threadIdx.x;
  if (idx >= 160 * 128) return;
  int kk = idx >> 7, f = idx & 127;
  int blk = kk >> 5, c = kk & 31;
  const float* W = (f < 64) ? Wz : Wh;
  int fl = f & 63;
  float v;
  if (blk == 0)      v = W[c * 64 + fl] + W[18432 + c * 64 + fl];
  else if (blk == 1) v = W[6144 + c * 64 + fl];
  else if (blk == 2) v = W[18432 + 6144 + c * 64 + fl];
  else if (blk == 3) v = W[2 * 6144 + c * 64 + fl];
  else               v = W[18432 + 2 * 6144 + c * 64 + fl];
  Weff[idx] = v;
}

// ---- register-blocked GEMM + GRU epilogue: 64 rows x 128 cols/block, K-chunk 80.
//      thread = 4 rows x 4 f x 2 gates -> 32 FMA per k-iter vs ~6 mem issues. ----
__global__ __launch_bounds__(256) void k_gemm(const float* __restrict__ X, const float* __restrict__ T1o,
                                              const float* __restrict__ T1i, const float* __restrict__ T2o,
                                              const float* __restrict__ T2i,
                                              const float* __restrict__ Weff,
                                              const float* __restrict__ bz, const float* __restrict__ bh,
                                              float* __restrict__ out) {
  __shared__ float Ws[80][128];   // 40960 B
  __shared__ float Fs[64][84];    // 21504 B (pad 80->84: 2-way max on fa reads, free)
  const int tid = threadIdx.x;
  const int tx = tid & 15, ty = tid >> 4;
  const int rb = blockIdx.x * 64;
  float accz[4][4] = {{0.f}}, acch[4][4] = {{0.f}};

  for (int kc = 0; kc < 160; kc += 80) {
    __syncthreads();
    // stage W chunk: 80x128 floats = 2560 float4, 10/thread, coalesced
    for (int i = 0; i < 10; ++i) {
      int q = tid + i * 256;
      int row = q >> 5, cv = q & 31;
      *(float4*)&Ws[row][cv * 4] = *(const float4*)&Weff[(kc + row) * 128 + cv * 4];
    }
    // stage F chunk: 64 rows x 20 float4 (80 k-cols) from 5 separate 32-col arrays
    for (int i = 0; i < 5; ++i) {
      int q = tid + i * 256;
      int row = q / 20, kv = q % 20;
      int gr = rb + row;
      int gc = kc + kv * 4;          // global k-col, float4-aligned, within one 32-block
      int blk = gc >> 5, off = gc & 31;
      const float* base = (blk == 0) ? X : (blk == 1) ? T1o : (blk == 2) ? T1i : (blk == 3) ? T2o : T2i;
      float4 v = make_float4(0.f, 0.f, 0.f, 0.f);
      if (gr < NN) v = *(const float4*)&base[gr * 32 + off];
      *(float4*)&Fs[row][kv * 4] = v;
    }
    __syncthreads();
    for (int k = 0; k < 80; ++k) {
      float fa[4];
#pragma unroll
      for (int ri = 0; ri < 4; ++ri) fa[ri] = Fs[ty * 4 + ri][k];
      float4 wz = *(float4*)&Ws[k][tx * 4];
      float4 wh = *(float4*)&Ws[k][64 + tx * 4];
#pragma unroll
      for (int ri = 0; ri < 4; ++ri) {
        accz[ri][0] += fa[ri] * wz.x; accz[ri][1] += fa[ri] * wz.y;
        accz[ri][2] += fa[ri] * wz.z; accz[ri][3] += fa[ri] * wz.w;
        acch[ri][0] += fa[ri] * wh.x; acch[ri][1] += fa[ri] * wh.y;
        acch[ri][2] += fa[ri] * wh.z; acch[ri][3] += fa[ri] * wh.w;
      }
    }
  }

  const float4 bzv = *(const float4*)&bz[tx * 4];
  const float4 bhv = *(const float4*)&bh[tx * 4];
#pragma unroll
  for (int ri = 0; ri < 4; ++ri) {
    int r = rb + ty * 4 + ri;
    if (r < NN) {
      float4 o;
      float z, h;
      z = 1.f / (1.f + expf(-(accz[ri][0] + bzv.x))); h = tanhf(acch[ri][0] + bhv.x); o.x = (1.f - z) * h;
      z = 1.f / (1.f + expf(-(accz[ri][1] + bzv.y))); h = tanhf(acch[ri][1] + bhv.y); o.y = (1.f - z) * h;
      z = 1.f / (1.f + expf(-(accz[ri][2] + bzv.z))); h = tanhf(acch[ri][2] + bhv.z); o.z = (1.f - z) * h;
      z = 1.f / (1.f + expf(-(accz[ri][3] + bzv.w))); h = tanhf(acch[ri][3] + bhv.w); o.w = (1.f - z) * h;
      *(float4*)&out[r * 64 + tx * 4] = o;
    }
  }
}

// ---------------- launch ----------------
extern "C" void kernel_launch(void* const* d_in, const int* in_sizes, int n_in,
                              void* d_out, int out_size, void* d_ws, size_t ws_size,
                              hipStream_t stream) {
  const float* X  = (const float*)d_in[0];
  const int*   ei = (const int*)d_in[1];
  const float* ew = (const float*)d_in[2];
  const float* Wz = (const float*)d_in[3];
  const float* bz = (const float*)d_in[4];
  const float* Wh = (const float*)d_in[7];
  const float* bh = (const float*)d_in[8];
  float* out = (float*)d_out;
  const int* src = ei;
  const int* dst = ei + NE;

  char* p = (char*)d_ws;
  auto alloc = [&](size_t bytes) -> char* {
    char* r = p;
    p += (bytes + 255) & ~(size_t)255;
    return r;
  };
  float* T1o     = (float*)alloc((size_t)NN * 32 * 4);
  float* T1i     = (float*)alloc((size_t)NN * 32 * 4);
  float* T2o     = (float*)alloc((size_t)NN * 32 * 4);
  float* T2i     = (float*)alloc((size_t)NN * 32 * 4);
  int*   bucket  = (int*)alloc((size_t)NE * 4);
  int*   col_fwd = (int*)alloc((size_t)NE * 4);
  float* rnrm    = (float*)alloc((size_t)NE * 4);
  int*   sp      = (int*)alloc((NN + 1) * 4);
  int*   rptr    = (int*)alloc((NN + 1) * 4);
  int*   cnt     = (int*)alloc(NN * 4);
  int*   fill    = (int*)alloc(NN * 4);
  int*   partial = (int*)alloc(64 * 4);
  float* dout    = (float*)alloc(NN * 4);
  float* din     = (float*)alloc(NN * 4);
  float* Weff    = (float*)alloc(160 * 128 * 4);
  int*   s0      = (int*)alloc(4);

  hipMemsetAsync(cnt, 0, NN * 4, stream);
  hipMemsetAsync(fill, 0, NN * 4, stream);

  k_rowdeg<<<196, 256, 0, stream>>>(src, ew, rptr, dout);
  k_cnt<<<3125, 256, 0, stream>>>(dst, cnt);
  k_scan1<<<49, 1024, 0, stream>>>(cnt, sp, partial);
  k_scan2<<<1, 64, 0, stream>>>(partial, 49);
  k_scan3<<<196, 256, 0, stream>>>(sp, partial);
  k_bucket<<<3125, 256, 0, stream>>>(dst, sp, fill, bucket);
  k_sort<<<196, 256, 0, stream>>>(sp, bucket);
  k_din<<<1563, 256, 0, stream>>>(sp, bucket, ew, din);
  k_s0<<<1, 64, 0, stream>>>(sp, bucket, src, s0);
  k_edge<<<3125, 256, 0, stream>>>(bucket, src, s0, din, col_fwd, rnrm);

  // T1o = Pf(X) (CSC gather, nrm from dout), T1i = Pr(X) (CSR gather, rnrm) — fused
  k_prop2<<<3125, 256, 0, stream>>>(X, sp, col_fwd, nullptr, dout, T1o,
                                    X, rptr, dst, rnrm, nullptr, T1i, nullptr, 1.f);
  // T2 = 2*P(T1) - X (fused Chebyshev), pair fused
  k_prop2<<<3125, 256, 0, stream>>>(T1o, sp, col_fwd, nullptr, dout, T2o,
                                    T1i, rptr, dst, rnrm, nullptr, T2i, X, 2.f);

  k_weff<<<80, 256, 0, stream>>>(Wz, Wh, Weff);
  k_gemm<<<782, 256, 0, stream>>>(X, T1o, T1i, T2o, T2i, Weff, bz, bh, out);
}

// Round 7
// 296.164 us; speedup vs baseline: 1.3497x; 1.3497x over previous
//
#include <hip/hip_runtime.h>
#include <cmath>

#define NN 50000
#define NE 800000
// int32-overflow boundary of the reference's argsort key (jax x64 disabled):
// key = dst*50000+src wraps for dst>42949, or dst==42949 && src>=33648.
// VERIFIED round 3: jax order = rotate(bucket, s0), norm indexed by UNROTATED j
// (rnrm[bucket[(j+s0)%NE]] = 1/din[src[j]], src = RAW src array).
#define DST_HI 42949
#define SRC_CUT 33648

// ---- rptr (CSR by src, binary search) + dout segment-sum, fused ----
__global__ __launch_bounds__(256) void k_rowdeg(const int* __restrict__ src, const float* __restrict__ w,
                                                int* __restrict__ rptr, float* __restrict__ dout) {
  int i = blockIdx.x * 256 + threadIdx.x;
  if (i >= NN) return;
  int lo = 0, hi = NE;
  while (lo < hi) { int m = (lo + hi) >> 1; if (src[m] < i) lo = m + 1; else hi = m; }
  int lo2 = lo, hi2 = NE;
  while (lo2 < hi2) { int m = (lo2 + hi2) >> 1; if (src[m] < i + 1) lo2 = m + 1; else hi2 = m; }
  rptr[i] = lo;
  if (i == NN - 1) rptr[NN] = lo2;
  float a = 0.f;
  for (int p = lo; p < lo2; ++p) a += w[p];
  dout[i] = a;
}

// ---- ONE atomic pass: histogram + arrival rank (rank makes the scatter atomic-free) ----
__global__ __launch_bounds__(256) void k_rank(const int* __restrict__ dst, int* __restrict__ cnt,
                                              int* __restrict__ rank) {
  int e = blockIdx.x * 256 + threadIdx.x;
  if (e >= NE) return;
  rank[e] = atomicAdd(&cnt[dst[e]], 1);
}

// ---- 3-kernel exclusive scan of cnt -> sp (sp[NN] = NE) ----
__global__ void k_scan1(const int* __restrict__ cnt, int* __restrict__ outp, int* __restrict__ partials) {
  __shared__ int tmp[1024];
  int i = blockIdx.x * 1024 + threadIdx.x;
  int v = (i < NN) ? cnt[i] : 0;
  tmp[threadIdx.x] = v;
  __syncthreads();
  for (int off = 1; off < 1024; off <<= 1) {
    int t = (threadIdx.x >= (unsigned)off) ? tmp[threadIdx.x - off] : 0;
    __syncthreads();
    tmp[threadIdx.x] += t;
    __syncthreads();
  }
  if (i < NN) outp[i] = tmp[threadIdx.x] - v;  // exclusive
  if (threadIdx.x == 1023) partials[blockIdx.x] = tmp[1023];
}

__global__ void k_scan2(int* __restrict__ partials, int nb) {
  if (threadIdx.x == 0 && blockIdx.x == 0) {
    int s = 0;
    for (int i = 0; i < nb; ++i) { int v = partials[i]; partials[i] = s; s += v; }
  }
}

__global__ __launch_bounds__(256) void k_scan3(int* __restrict__ outp, const int* __restrict__ partials) {
  int i = blockIdx.x * 256 + threadIdx.x;
  if (i < NN) outp[i] += partials[i >> 10];
  else if (i == NN) outp[i] = NE;
}

// ---- atomic-free scatter into dst buckets using precomputed arrival rank ----
__global__ __launch_bounds__(256) void k_scatter(const int* __restrict__ dst, const int* __restrict__ sp,
                                                 const int* __restrict__ rank, int* __restrict__ bucket) {
  int e = blockIdx.x * 256 + threadIdx.x;
  if (e >= NE) return;
  bucket[sp[dst[e]] + rank[e]] = e;
}

// ---- wave-per-bucket bitonic sort (64 lanes, shfl_xor; == argsort by true (dst,src)) ----
__global__ __launch_bounds__(256) void k_sortw(const int* __restrict__ sp, int* __restrict__ bucket) {
  int wv = (blockIdx.x * 256 + threadIdx.x) >> 6;
  int lane = threadIdx.x & 63;
  if (wv >= NN) return;
  int b0 = sp[wv], b1 = sp[wv + 1];
  int n = b1 - b0;
  if (n <= 1) return;
  if (n > 64) {  // safety fallback (Poisson(16) never hits this)
    if (lane == 0) {
      for (int i = b0 + 1; i < b1; ++i) {
        int v = bucket[i]; int j = i - 1;
        while (j >= b0 && bucket[j] > v) { bucket[j + 1] = bucket[j]; --j; }
        bucket[j + 1] = v;
      }
    }
    return;
  }
  int v = (lane < n) ? bucket[b0 + lane] : 0x7fffffff;
#pragma unroll
  for (int k = 2; k <= 64; k <<= 1) {
#pragma unroll
    for (int j = k >> 1; j > 0; j >>= 1) {
      int o = __shfl_xor(v, j, 64);
      bool lower = (lane & j) == 0;
      bool asc = (lane & k) == 0;
      int mn = min(v, o), mx = max(v, o);
      v = (lower == asc) ? mn : mx;
    }
  }
  if (lane < n) bucket[b0 + lane] = v;
}

// ---- din: gather segment sum over dst-buckets (order-invariant), 8 lanes/node ----
__global__ __launch_bounds__(256) void k_din(const int* __restrict__ sp, const int* __restrict__ bucket,
                                             const float* __restrict__ w, float* __restrict__ din) {
  int t = blockIdx.x * 256 + threadIdx.x;
  int r = t >> 3;
  if (r >= NN) return;
  int lane = t & 7;
  int b = sp[r], e = sp[r + 1];
  float a = 0.f;
  for (int j = b + lane; j < e; j += 8) a += w[bucket[j]];
  a += __shfl_down(a, 4, 8);
  a += __shfl_down(a, 2, 8);
  a += __shfl_down(a, 1, 8);
  if (lane == 0) din[r] = a;
}

// ---- rotation offset s0 = #edges with non-overflowing int32 key ----
__global__ void k_s0(const int* __restrict__ sp, const int* __restrict__ bucket,
                     const int* __restrict__ src, int* __restrict__ s0) {
  if (threadIdx.x != 0 || blockIdx.x != 0) return;
  int b0 = sp[DST_HI], b1 = sp[DST_HI + 1];
  int c = b0;
  for (int j = b0; j < b1; ++j)
    if (src[bucket[j]] < SRC_CUT) ++c;
  *s0 = c;
}

// ---- per-edge arrays (both norms PRECOMPUTED — streaming reads in the props):
//   fwd: col_fwd[j] = src[bucket[j]], nrm_fwd[j] = 1/dout[col]
//   rev: rnrm[bucket[(j+s0)%NE]] = 1/din[src[j]]  (rotation bijection, verified) ----
__global__ __launch_bounds__(256) void k_edge(const int* __restrict__ bucket, const int* __restrict__ src,
                                              const int* __restrict__ s0p,
                                              const float* __restrict__ dout, const float* __restrict__ din,
                                              int* __restrict__ col_fwd, float* __restrict__ nrm_fwd,
                                              float* __restrict__ rnrm) {
  int j = blockIdx.x * 256 + threadIdx.x;
  if (j >= NE) return;
  int e = bucket[j];
  int s = src[e];
  col_fwd[j] = s;
  nrm_fwd[j] = 1.0f / dout[s];
  int idx = j + *s0p;
  if (idx >= NE) idx -= NE;
  rnrm[bucket[idx]] = 1.0f / din[src[j]];
}

// ---- fused pair of gather props: 8 lanes/row, float4/lane, edge loop UNROLLED x4
//      (4 independent gathers in flight -> hides L2/HBM latency).
//      out = mul*acc - sub (sub==nullptr -> acc) ----
__global__ __launch_bounds__(256) void k_prop2(const float* __restrict__ inA, const int* __restrict__ rpA,
                                               const int* __restrict__ colsA, const float* __restrict__ nrmA,
                                               float* __restrict__ outA,
                                               const float* __restrict__ inB, const int* __restrict__ rpB,
                                               const int* __restrict__ colsB, const float* __restrict__ nrmB,
                                               float* __restrict__ outB,
                                               const float* __restrict__ sub, float mul) {
  int t = blockIdx.x * 256 + threadIdx.x;
  const int half = NN * 8;
  const float* in; const int* rp; const int* cols; const float* nrm; float* out;
  if (t < half) { in = inA; rp = rpA; cols = colsA; nrm = nrmA; out = outA; }
  else          { in = inB; rp = rpB; cols = colsB; nrm = nrmB; out = outB; t -= half; }
  int r = t >> 3;
  if (r >= NN) return;
  int c4 = (t & 7) * 4;
  int b = rp[r], e2 = rp[r + 1];
  float a0x = 0.f, a0y = 0.f, a0z = 0.f, a0w = 0.f;
  float a1x = 0.f, a1y = 0.f, a1z = 0.f, a1w = 0.f;
  int p = b;
  for (; p + 4 <= e2; p += 4) {
    int c0 = cols[p], c1 = cols[p + 1], c2 = cols[p + 2], c3 = cols[p + 3];
    float w0 = nrm[p], w1 = nrm[p + 1], w2 = nrm[p + 2], w3 = nrm[p + 3];
    const float4 x0 = *(const float4*)&in[c0 * 32 + c4];
    const float4 x1 = *(const float4*)&in[c1 * 32 + c4];
    const float4 x2 = *(const float4*)&in[c2 * 32 + c4];
    const float4 x3 = *(const float4*)&in[c3 * 32 + c4];
    a0x += w0 * x0.x; a0y += w0 * x0.y; a0z += w0 * x0.z; a0w += w0 * x0.w;
    a1x += w1 * x1.x; a1y += w1 * x1.y; a1z += w1 * x1.z; a1w += w1 * x1.w;
    a0x += w2 * x2.x; a0y += w2 * x2.y; a0z += w2 * x2.z; a0w += w2 * x2.w;
    a1x += w3 * x3.x; a1y += w3 * x3.y; a1z += w3 * x3.z; a1w += w3 * x3.w;
  }
  for (; p < e2; ++p) {
    int col = cols[p];
    float w = nrm[p];
    const float4 xv = *(const float4*)&in[col * 32 + c4];
    a0x += w * xv.x; a0y += w * xv.y; a0z += w * xv.z; a0w += w * xv.w;
  }
  float ax = a0x + a1x, ay = a0y + a1y, az = a0z + a1z, aw = a0w + a1w;
  float4 o;
  if (sub) {
    const float4 s = *(const float4*)&sub[r * 32 + c4];
    o.x = mul * ax - s.x; o.y = mul * ay - s.y; o.z = mul * az - s.z; o.w = mul * aw - s.w;
  } else {
    o.x = ax; o.y = ay; o.z = az; o.w = aw;
  }
  *(float4*)&out[r * 32 + c4] = o;
}

// ---- effective weights (160 x 128): rows = [X|T1o|T1i|T2o|T2i]x32, cols 0..63=z, 64..127=h ----
__global__ __launch_bounds__(256) void k_weff(const float* __restrict__ Wz, const float* __restrict__ Wh,
                                              float* __restrict__ Weff) {
  int idx = blockIdx.x * 256 + threadIdx.x;
  if (idx >= 160 * 128) return;
  int kk = idx >> 7, f = idx & 127;
  int blk = kk >> 5, c = kk & 31;
  const float* W = (f < 64) ? Wz : Wh;
  int fl = f & 63;
  float v;
  if (blk == 0)      v = W[c * 64 + fl] + W[18432 + c * 64 + fl];
  else if (blk == 1) v = W[6144 + c * 64 + fl];
  else if (blk == 2) v = W[18432 + 6144 + c * 64 + fl];
  else if (blk == 3) v = W[2 * 6144 + c * 64 + fl];
  else               v = W[18432 + 2 * 6144 + c * 64 + fl];
  Weff[idx] = v;
}

// ---- register-blocked GEMM + GRU epilogue (validated round 6): 64x128 tile, K-chunk 80 ----
__global__ __launch_bounds__(256) void k_gemm(const float* __restrict__ X, const float* __restrict__ T1o,
                                              const float* __restrict__ T1i, const float* __restrict__ T2o,
                                              const float* __restrict__ T2i,
                                              const float* __restrict__ Weff,
                                              const float* __restrict__ bz, const float* __restrict__ bh,
                                              float* __restrict__ out) {
  __shared__ float Ws[80][128];
  __shared__ float Fs[64][84];
  const int tid = threadIdx.x;
  const int tx = tid & 15, ty = tid >> 4;
  const int rb = blockIdx.x * 64;
  float accz[4][4] = {{0.f}}, acch[4][4] = {{0.f}};

  for (int kc = 0; kc < 160; kc += 80) {
    __syncthreads();
    for (int i = 0; i < 10; ++i) {
      int q = tid + i * 256;
      int row = q >> 5, cv = q & 31;
      *(float4*)&Ws[row][cv * 4] = *(const float4*)&Weff[(kc + row) * 128 + cv * 4];
    }
    for (int i = 0; i < 5; ++i) {
      int q = tid + i * 256;
      int row = q / 20, kv = q % 20;
      int gr = rb + row;
      int gc = kc + kv * 4;
      int blk = gc >> 5, off = gc & 31;
      const float* base = (blk == 0) ? X : (blk == 1) ? T1o : (blk == 2) ? T1i : (blk == 3) ? T2o : T2i;
      float4 v = make_float4(0.f, 0.f, 0.f, 0.f);
      if (gr < NN) v = *(const float4*)&base[gr * 32 + off];
      *(float4*)&Fs[row][kv * 4] = v;
    }
    __syncthreads();
    for (int k = 0; k < 80; ++k) {
      float fa[4];
#pragma unroll
      for (int ri = 0; ri < 4; ++ri) fa[ri] = Fs[ty * 4 + ri][k];
      float4 wz = *(float4*)&Ws[k][tx * 4];
      float4 wh = *(float4*)&Ws[k][64 + tx * 4];
#pragma unroll
      for (int ri = 0; ri < 4; ++ri) {
        accz[ri][0] += fa[ri] * wz.x; accz[ri][1] += fa[ri] * wz.y;
        accz[ri][2] += fa[ri] * wz.z; accz[ri][3] += fa[ri] * wz.w;
        acch[ri][0] += fa[ri] * wh.x; acch[ri][1] += fa[ri] * wh.y;
        acch[ri][2] += fa[ri] * wh.z; acch[ri][3] += fa[ri] * wh.w;
      }
    }
  }

  const float4 bzv = *(const float4*)&bz[tx * 4];
  const float4 bhv = *(const float4*)&bh[tx * 4];
#pragma unroll
  for (int ri = 0; ri < 4; ++ri) {
    int r = rb + ty * 4 + ri;
    if (r < NN) {
      float4 o;
      float z, h;
      z = 1.f / (1.f + expf(-(accz[ri][0] + bzv.x))); h = tanhf(acch[ri][0] + bhv.x); o.x = (1.f - z) * h;
      z = 1.f / (1.f + expf(-(accz[ri][1] + bzv.y))); h = tanhf(acch[ri][1] + bhv.y); o.y = (1.f - z) * h;
      z = 1.f / (1.f + expf(-(accz[ri][2] + bzv.z))); h = tanhf(acch[ri][2] + bhv.z); o.z = (1.f - z) * h;
      z = 1.f / (1.f + expf(-(accz[ri][3] + bzv.w))); h = tanhf(acch[ri][3] + bhv.w); o.w = (1.f - z) * h;
      *(float4*)&out[r * 64 + tx * 4] = o;
    }
  }
}

// ---------------- launch ----------------
extern "C" void kernel_launch(void* const* d_in, const int* in_sizes, int n_in,
                              void* d_out, int out_size, void* d_ws, size_t ws_size,
                              hipStream_t stream) {
  const float* X  = (const float*)d_in[0];
  const int*   ei = (const int*)d_in[1];
  const float* ew = (const float*)d_in[2];
  const float* Wz = (const float*)d_in[3];
  const float* bz = (const float*)d_in[4];
  const float* Wh = (const float*)d_in[7];
  const float* bh = (const float*)d_in[8];
  float* out = (float*)d_out;
  const int* src = ei;
  const int* dst = ei + NE;

  char* p = (char*)d_ws;
  auto alloc = [&](size_t bytes) -> char* {
    char* r = p;
    p += (bytes + 255) & ~(size_t)255;
    return r;
  };
  float* T1o     = (float*)alloc((size_t)NN * 32 * 4);
  float* T1i     = (float*)alloc((size_t)NN * 32 * 4);
  float* T2o     = (float*)alloc((size_t)NN * 32 * 4);
  float* T2i     = (float*)alloc((size_t)NN * 32 * 4);
  int*   bucket  = (int*)alloc((size_t)NE * 4);
  int*   rank    = (int*)alloc((size_t)NE * 4);
  int*   col_fwd = (int*)alloc((size_t)NE * 4);
  float* nrm_fwd = (float*)alloc((size_t)NE * 4);
  float* rnrm    = (float*)alloc((size_t)NE * 4);
  int*   sp      = (int*)alloc((NN + 1) * 4);
  int*   rptr    = (int*)alloc((NN + 1) * 4);
  int*   cnt     = (int*)alloc(NN * 4);
  int*   partial = (int*)alloc(64 * 4);
  float* dout    = (float*)alloc(NN * 4);
  float* din     = (float*)alloc(NN * 4);
  float* Weff    = (float*)alloc(160 * 128 * 4);
  int*   s0      = (int*)alloc(4);

  hipMemsetAsync(cnt, 0, NN * 4, stream);

  k_rowdeg<<<196, 256, 0, stream>>>(src, ew, rptr, dout);
  k_rank<<<3125, 256, 0, stream>>>(dst, cnt, rank);       // the ONE atomic pass
  k_scan1<<<49, 1024, 0, stream>>>(cnt, sp, partial);
  k_scan2<<<1, 64, 0, stream>>>(partial, 49);
  k_scan3<<<196, 256, 0, stream>>>(sp, partial);
  k_scatter<<<3125, 256, 0, stream>>>(dst, sp, rank, bucket);  // atomic-free
  k_sortw<<<12500, 256, 0, stream>>>(sp, bucket);              // wave bitonic
  k_din<<<1563, 256, 0, stream>>>(sp, bucket, ew, din);
  k_s0<<<1, 64, 0, stream>>>(sp, bucket, src, s0);
  k_edge<<<3125, 256, 0, stream>>>(bucket, src, s0, dout, din, col_fwd, nrm_fwd, rnrm);

  // T1o = Pf(X) (CSC gather), T1i = Pr(X) (CSR gather) — fused, unrolled
  k_prop2<<<3125, 256, 0, stream>>>(X, sp, col_fwd, nrm_fwd, T1o,
                                    X, rptr, dst, rnrm, T1i, nullptr, 1.f);
  // T2 = 2*P(T1) - X (fused Chebyshev), pair fused
  k_prop2<<<3125, 256, 0, stream>>>(T1o, sp, col_fwd, nrm_fwd, T2o,
                                    T1i, rptr, dst, rnrm, T2i, X, 2.f);

  k_weff<<<80, 256, 0, stream>>>(Wz, Wh, Weff);
  k_gemm<<<782, 256, 0, stream>>>(X, T1o, T1i, T2o, T2i, Weff, bz, bh, out);
}

// Round 8
// 289.277 us; speedup vs baseline: 1.3819x; 1.0238x over previous
//
#include <hip/hip_runtime.h>
#include <cmath>

#define NN 50000
#define NE 800000
// int32-overflow boundary of the reference's argsort key (jax x64 disabled):
// key = dst*50000+src wraps for dst>42949, or dst==42949 && src>=33648.
// VERIFIED round 3: jax order = rotate(bucket, s0), norm indexed by UNROTATED j
// (rnrm[bucket[(j+s0)%NE]] = 1/din[src[j]], src = RAW src array).
#define DST_HI 42949
#define SRC_CUT 33648

// ---- rptr (CSR by src, binary search) + dout segment-sum, fused ----
__global__ __launch_bounds__(256) void k_rowdeg(const int* __restrict__ src, const float* __restrict__ w,
                                                int* __restrict__ rptr, float* __restrict__ dout) {
  int i = blockIdx.x * 256 + threadIdx.x;
  if (i >= NN) return;
  int lo = 0, hi = NE;
  while (lo < hi) { int m = (lo + hi) >> 1; if (src[m] < i) lo = m + 1; else hi = m; }
  int lo2 = lo, hi2 = NE;
  while (lo2 < hi2) { int m = (lo2 + hi2) >> 1; if (src[m] < i + 1) lo2 = m + 1; else hi2 = m; }
  rptr[i] = lo;
  if (i == NN - 1) rptr[NN] = lo2;
  float a = 0.f;
  for (int p = lo; p < lo2; ++p) a += w[p];
  dout[i] = a;
}

// ---- ONE atomic pass: histogram + arrival rank (rank makes the scatter atomic-free) ----
__global__ __launch_bounds__(256) void k_rank(const int* __restrict__ dst, int* __restrict__ cnt,
                                              int* __restrict__ rank) {
  int e = blockIdx.x * 256 + threadIdx.x;
  if (e >= NE) return;
  rank[e] = atomicAdd(&cnt[dst[e]], 1);
}

// ---- 3-kernel exclusive scan of cnt -> sp (sp[NN] = NE) ----
__global__ void k_scan1(const int* __restrict__ cnt, int* __restrict__ outp, int* __restrict__ partials) {
  __shared__ int tmp[1024];
  int i = blockIdx.x * 1024 + threadIdx.x;
  int v = (i < NN) ? cnt[i] : 0;
  tmp[threadIdx.x] = v;
  __syncthreads();
  for (int off = 1; off < 1024; off <<= 1) {
    int t = (threadIdx.x >= (unsigned)off) ? tmp[threadIdx.x - off] : 0;
    __syncthreads();
    tmp[threadIdx.x] += t;
    __syncthreads();
  }
  if (i < NN) outp[i] = tmp[threadIdx.x] - v;  // exclusive
  if (threadIdx.x == 1023) partials[blockIdx.x] = tmp[1023];
}

__global__ void k_scan2(int* __restrict__ partials, int nb) {
  if (threadIdx.x == 0 && blockIdx.x == 0) {
    int s = 0;
    for (int i = 0; i < nb; ++i) { int v = partials[i]; partials[i] = s; s += v; }
  }
}

__global__ __launch_bounds__(256) void k_scan3(int* __restrict__ outp, const int* __restrict__ partials) {
  int i = blockIdx.x * 256 + threadIdx.x;
  if (i < NN) outp[i] += partials[i >> 10];
  else if (i == NN) outp[i] = NE;
}

// ---- atomic-free scatter into dst buckets using precomputed arrival rank ----
__global__ __launch_bounds__(256) void k_scatter(const int* __restrict__ dst, const int* __restrict__ sp,
                                                 const int* __restrict__ rank, int* __restrict__ bucket) {
  int e = blockIdx.x * 256 + threadIdx.x;
  if (e >= NE) return;
  bucket[sp[dst[e]] + rank[e]] = e;
}

// ---- wave-per-bucket bitonic sort (64 lanes, shfl_xor; == argsort by true (dst,src)) ----
__global__ __launch_bounds__(256) void k_sortw(const int* __restrict__ sp, int* __restrict__ bucket) {
  int wv = (blockIdx.x * 256 + threadIdx.x) >> 6;
  int lane = threadIdx.x & 63;
  if (wv >= NN) return;
  int b0 = sp[wv], b1 = sp[wv + 1];
  int n = b1 - b0;
  if (n <= 1) return;
  if (n > 64) {  // safety fallback (Poisson(16) never hits this)
    if (lane == 0) {
      for (int i = b0 + 1; i < b1; ++i) {
        int v = bucket[i]; int j = i - 1;
        while (j >= b0 && bucket[j] > v) { bucket[j + 1] = bucket[j]; --j; }
        bucket[j + 1] = v;
      }
    }
    return;
  }
  int v = (lane < n) ? bucket[b0 + lane] : 0x7fffffff;
#pragma unroll
  for (int k = 2; k <= 64; k <<= 1) {
#pragma unroll
    for (int j = k >> 1; j > 0; j >>= 1) {
      int o = __shfl_xor(v, j, 64);
      bool lower = (lane & j) == 0;
      bool asc = (lane & k) == 0;
      int mn = min(v, o), mx = max(v, o);
      v = (lower == asc) ? mn : mx;
    }
  }
  if (lane < n) bucket[b0 + lane] = v;
}

// ---- din: gather segment sum over dst-buckets (order-invariant), 8 lanes/node ----
__global__ __launch_bounds__(256) void k_din(const int* __restrict__ sp, const int* __restrict__ bucket,
                                             const float* __restrict__ w, float* __restrict__ din) {
  int t = blockIdx.x * 256 + threadIdx.x;
  int r = t >> 3;
  if (r >= NN) return;
  int lane = t & 7;
  int b = sp[r], e = sp[r + 1];
  float a = 0.f;
  for (int j = b + lane; j < e; j += 8) a += w[bucket[j]];
  a += __shfl_down(a, 4, 8);
  a += __shfl_down(a, 2, 8);
  a += __shfl_down(a, 1, 8);
  if (lane == 0) din[r] = a;
}

// ---- per-edge arrays (norms PRECOMPUTED — streaming reads in the props), s0 inlined:
//   fwd: col_fwd[j] = src[bucket[j]], nrm_fwd[j] = 1/dout[col]
//   rev: rnrm[bucket[(j+s0)%NE]] = 1/din[src[j]]  (rotation bijection, verified) ----
__global__ __launch_bounds__(256) void k_edge(const int* __restrict__ sp, const int* __restrict__ bucket,
                                              const int* __restrict__ src,
                                              const float* __restrict__ dout, const float* __restrict__ din,
                                              int* __restrict__ col_fwd, float* __restrict__ nrm_fwd,
                                              float* __restrict__ rnrm) {
  __shared__ int s0s;
  if (threadIdx.x < 64) {
    int b0 = sp[DST_HI], b1 = sp[DST_HI + 1];
    int n = b1 - b0;
    if (n <= 64) {
      unsigned long long m = __ballot(threadIdx.x < n && src[bucket[b0 + threadIdx.x]] < SRC_CUT);
      if (threadIdx.x == 0) s0s = b0 + (int)__popcll(m);
    } else if (threadIdx.x == 0) {
      int c = b0;
      for (int j = b0; j < b1; ++j)
        if (src[bucket[j]] < SRC_CUT) ++c;
      s0s = c;
    }
  }
  __syncthreads();
  int j = blockIdx.x * 256 + threadIdx.x;
  if (j >= NE) return;
  int e = bucket[j];
  int s = src[e];
  col_fwd[j] = s;
  nrm_fwd[j] = 1.0f / dout[s];
  int idx = j + s0s;
  if (idx >= NE) idx -= NE;
  rnrm[bucket[idx]] = 1.0f / din[src[j]];
}

// ---- fused pair of gather props: 8 lanes/row, float4/lane, edge loop UNROLLED x4 ----
__global__ __launch_bounds__(256) void k_prop2(const float* __restrict__ inA, const int* __restrict__ rpA,
                                               const int* __restrict__ colsA, const float* __restrict__ nrmA,
                                               float* __restrict__ outA,
                                               const float* __restrict__ inB, const int* __restrict__ rpB,
                                               const int* __restrict__ colsB, const float* __restrict__ nrmB,
                                               float* __restrict__ outB,
                                               const float* __restrict__ sub, float mul) {
  int t = blockIdx.x * 256 + threadIdx.x;
  const int half = NN * 8;
  const float* in; const int* rp; const int* cols; const float* nrm; float* out;
  if (t < half) { in = inA; rp = rpA; cols = colsA; nrm = nrmA; out = outA; }
  else          { in = inB; rp = rpB; cols = colsB; nrm = nrmB; out = outB; t -= half; }
  int r = t >> 3;
  if (r >= NN) return;
  int c4 = (t & 7) * 4;
  int b = rp[r], e2 = rp[r + 1];
  float a0x = 0.f, a0y = 0.f, a0z = 0.f, a0w = 0.f;
  float a1x = 0.f, a1y = 0.f, a1z = 0.f, a1w = 0.f;
  int p = b;
  for (; p + 4 <= e2; p += 4) {
    int c0 = cols[p], c1 = cols[p + 1], c2 = cols[p + 2], c3 = cols[p + 3];
    float w0 = nrm[p], w1 = nrm[p + 1], w2 = nrm[p + 2], w3 = nrm[p + 3];
    const float4 x0 = *(const float4*)&in[c0 * 32 + c4];
    const float4 x1 = *(const float4*)&in[c1 * 32 + c4];
    const float4 x2 = *(const float4*)&in[c2 * 32 + c4];
    const float4 x3 = *(const float4*)&in[c3 * 32 + c4];
    a0x += w0 * x0.x; a0y += w0 * x0.y; a0z += w0 * x0.z; a0w += w0 * x0.w;
    a1x += w1 * x1.x; a1y += w1 * x1.y; a1z += w1 * x1.z; a1w += w1 * x1.w;
    a0x += w2 * x2.x; a0y += w2 * x2.y; a0z += w2 * x2.z; a0w += w2 * x2.w;
    a1x += w3 * x3.x; a1y += w3 * x3.y; a1z += w3 * x3.z; a1w += w3 * x3.w;
  }
  for (; p < e2; ++p) {
    int col = cols[p];
    float w = nrm[p];
    const float4 xv = *(const float4*)&in[col * 32 + c4];
    a0x += w * xv.x; a0y += w * xv.y; a0z += w * xv.z; a0w += w * xv.w;
  }
  float ax = a0x + a1x, ay = a0y + a1y, az = a0z + a1z, aw = a0w + a1w;
  float4 o;
  if (sub) {
    const float4 s = *(const float4*)&sub[r * 32 + c4];
    o.x = mul * ax - s.x; o.y = mul * ay - s.y; o.z = mul * az - s.z; o.w = mul * aw - s.w;
  } else {
    o.x = ax; o.y = ay; o.z = az; o.w = aw;
  }
  *(float4*)&out[r * 32 + c4] = o;
}

// ---- effective weights (160 x 128): rows = [X|T1o|T1i|T2o|T2i]x32, cols 0..63=z, 64..127=h ----
__global__ __launch_bounds__(256) void k_weff(const float* __restrict__ Wz, const float* __restrict__ Wh,
                                              float* __restrict__ Weff) {
  int idx = blockIdx.x * 256 + threadIdx.x;
  if (idx >= 160 * 128) return;
  int kk = idx >> 7, f = idx & 127;
  int blk = kk >> 5, c = kk & 31;
  const float* W = (f < 64) ? Wz : Wh;
  int fl = f & 63;
  float v;
  if (blk == 0)      v = W[c * 64 + fl] + W[18432 + c * 64 + fl];
  else if (blk == 1) v = W[6144 + c * 64 + fl];
  else if (blk == 2) v = W[18432 + 6144 + c * 64 + fl];
  else if (blk == 3) v = W[2 * 6144 + c * 64 + fl];
  else               v = W[18432 + 2 * 6144 + c * 64 + fl];
  Weff[idx] = v;
}

// ---- register-blocked GEMM + GRU epilogue: 64x128 tile, K-chunk 32 (LDS 25.6 KB for occupancy).
//      thread = 4 rows x 4 f x 2 gates. Round 7 lesson: 62 KB LDS -> 2 blocks/CU -> 13% occ. ----
__global__ __launch_bounds__(256) void k_gemm(const float* __restrict__ X, const float* __restrict__ T1o,
                                              const float* __restrict__ T1i, const float* __restrict__ T2o,
                                              const float* __restrict__ T2i,
                                              const float* __restrict__ Weff,
                                              const float* __restrict__ bz, const float* __restrict__ bh,
                                              float* __restrict__ out) {
  __shared__ float Ws[32][128];   // 16384 B
  __shared__ float Fs[64][36];    // 9216 B (pad 32->36)
  const int tid = threadIdx.x;
  const int tx = tid & 15, ty = tid >> 4;
  const int rb = blockIdx.x * 64;
  float accz[4][4] = {{0.f}}, acch[4][4] = {{0.f}};

  for (int kc = 0; kc < 160; kc += 32) {
    __syncthreads();
    // stage W chunk: 32x128 = 1024 float4, 4/thread, coalesced
#pragma unroll
    for (int i = 0; i < 4; ++i) {
      int q = tid + i * 256;
      int row = q >> 5, cv = q & 31;
      *(float4*)&Ws[row][cv * 4] = *(const float4*)&Weff[(kc + row) * 128 + cv * 4];
    }
    // stage F chunk: 64 rows x 8 float4 = 512, 2/thread; chunk aligns with ONE source array
    const int blk = kc >> 5;
    const float* base = (blk == 0) ? X : (blk == 1) ? T1o : (blk == 2) ? T1i : (blk == 3) ? T2o : T2i;
#pragma unroll
    for (int i = 0; i < 2; ++i) {
      int q = tid + i * 256;
      int row = q >> 3, kv = q & 7;
      int gr = rb + row;
      float4 v = make_float4(0.f, 0.f, 0.f, 0.f);
      if (gr < NN) v = *(const float4*)&base[gr * 32 + kv * 4];
      *(float4*)&Fs[row][kv * 4] = v;
    }
    __syncthreads();
#pragma unroll
    for (int k = 0; k < 32; ++k) {
      float fa[4];
#pragma unroll
      for (int ri = 0; ri < 4; ++ri) fa[ri] = Fs[ty * 4 + ri][k];
      float4 wz = *(float4*)&Ws[k][tx * 4];
      float4 wh = *(float4*)&Ws[k][64 + tx * 4];
#pragma unroll
      for (int ri = 0; ri < 4; ++ri) {
        accz[ri][0] += fa[ri] * wz.x; accz[ri][1] += fa[ri] * wz.y;
        accz[ri][2] += fa[ri] * wz.z; accz[ri][3] += fa[ri] * wz.w;
        acch[ri][0] += fa[ri] * wh.x; acch[ri][1] += fa[ri] * wh.y;
        acch[ri][2] += fa[ri] * wh.z; acch[ri][3] += fa[ri] * wh.w;
      }
    }
  }

  const float4 bzv = *(const float4*)&bz[tx * 4];
  const float4 bhv = *(const float4*)&bh[tx * 4];
#pragma unroll
  for (int ri = 0; ri < 4; ++ri) {
    int r = rb + ty * 4 + ri;
    if (r < NN) {
      float4 o;
      float z, h;
      z = 1.f / (1.f + expf(-(accz[ri][0] + bzv.x))); h = tanhf(acch[ri][0] + bhv.x); o.x = (1.f - z) * h;
      z = 1.f / (1.f + expf(-(accz[ri][1] + bzv.y))); h = tanhf(acch[ri][1] + bhv.y); o.y = (1.f - z) * h;
      z = 1.f / (1.f + expf(-(accz[ri][2] + bzv.z))); h = tanhf(acch[ri][2] + bhv.z); o.z = (1.f - z) * h;
      z = 1.f / (1.f + expf(-(accz[ri][3] + bzv.w))); h = tanhf(acch[ri][3] + bhv.w); o.w = (1.f - z) * h;
      *(float4*)&out[r * 64 + tx * 4] = o;
    }
  }
}

// ---------------- launch ----------------
extern "C" void kernel_launch(void* const* d_in, const int* in_sizes, int n_in,
                              void* d_out, int out_size, void* d_ws, size_t ws_size,
                              hipStream_t stream) {
  const float* X  = (const float*)d_in[0];
  const int*   ei = (const int*)d_in[1];
  const float* ew = (const float*)d_in[2];
  const float* Wz = (const float*)d_in[3];
  const float* bz = (const float*)d_in[4];
  const float* Wh = (const float*)d_in[7];
  const float* bh = (const float*)d_in[8];
  float* out = (float*)d_out;
  const int* src = ei;
  const int* dst = ei + NE;

  char* p = (char*)d_ws;
  auto alloc = [&](size_t bytes) -> char* {
    char* r = p;
    p += (bytes + 255) & ~(size_t)255;
    return r;
  };
  float* T1o     = (float*)alloc((size_t)NN * 32 * 4);
  float* T1i     = (float*)alloc((size_t)NN * 32 * 4);
  float* T2o     = (float*)alloc((size_t)NN * 32 * 4);
  float* T2i     = (float*)alloc((size_t)NN * 32 * 4);
  int*   bucket  = (int*)alloc((size_t)NE * 4);
  int*   rank    = (int*)alloc((size_t)NE * 4);
  int*   col_fwd = (int*)alloc((size_t)NE * 4);
  float* nrm_fwd = (float*)alloc((size_t)NE * 4);
  float* rnrm    = (float*)alloc((size_t)NE * 4);
  int*   sp      = (int*)alloc((NN + 1) * 4);
  int*   rptr    = (int*)alloc((NN + 1) * 4);
  int*   cnt     = (int*)alloc(NN * 4);
  int*   partial = (int*)alloc(64 * 4);
  float* dout    = (float*)alloc(NN * 4);
  float* din     = (float*)alloc(NN * 4);
  float* Weff    = (float*)alloc(160 * 128 * 4);

  hipMemsetAsync(cnt, 0, NN * 4, stream);

  k_rowdeg<<<196, 256, 0, stream>>>(src, ew, rptr, dout);
  k_rank<<<3125, 256, 0, stream>>>(dst, cnt, rank);       // the ONE atomic pass
  k_scan1<<<49, 1024, 0, stream>>>(cnt, sp, partial);
  k_scan2<<<1, 64, 0, stream>>>(partial, 49);
  k_scan3<<<196, 256, 0, stream>>>(sp, partial);
  k_scatter<<<3125, 256, 0, stream>>>(dst, sp, rank, bucket);  // atomic-free
  k_sortw<<<12500, 256, 0, stream>>>(sp, bucket);              // wave bitonic
  k_din<<<1563, 256, 0, stream>>>(sp, bucket, ew, din);
  k_edge<<<3125, 256, 0, stream>>>(sp, bucket, src, dout, din, col_fwd, nrm_fwd, rnrm);

  // T1o = Pf(X) (CSC gather), T1i = Pr(X) (CSR gather) — fused, unrolled
  k_prop2<<<3125, 256, 0, stream>>>(X, sp, col_fwd, nrm_fwd, T1o,
                                    X, rptr, dst, rnrm, T1i, nullptr, 1.f);
  // T2 = 2*P(T1) - X (fused Chebyshev), pair fused
  k_prop2<<<3125, 256, 0, stream>>>(T1o, sp, col_fwd, nrm_fwd, T2o,
                                    T1i, rptr, dst, rnrm, T2i, X, 2.f);

  k_weff<<<80, 256, 0, stream>>>(Wz, Wh, Weff);
  k_gemm<<<782, 256, 0, stream>>>(X, T1o, T1i, T2o, T2i, Weff, bz, bh, out);
}